// Round 19
// baseline (106.032 us; speedup 1.0000x reference)
//
#include <hip/hip_runtime.h>

// MonarchLinear: x[16384,256] fp32, L[68,68,68], R[68,68,68], bias[4608] -> out[16384,4608] fp32.
//   t1[b,r,l] = sum_p x[b, r*68+p] * L[r,l,p]           (r<4; r==3 only p<52 valid)
//   out[b, s*68+l] = sum_{r<4} t1[b,r,l] * R[l,s,r] + bias[s*68+l]
//
// Round 19: r16 quarter-pipeline (B(q) store-drain overlaps A(q+1) compute)
// MINUS its one quantified flaw: the per-quarter j-loop re-ran B's 64-line
// R scatters 4x (+60 instr <-> +61us, r16). R/bias operands now come from a
// lane-contiguous pack Rp[j][q][tid] (r17's layout, proven correct+cheap),
// pack dispatch spread over 25 blocks (~launch overhead only).
// Structure: stage-x -> A(q0) -> { B(q) [coalesced Rp loads, stores] ->
// A(q+1) -> barrier }, disjoint t1s quarters, 4 blocks/CU.

typedef float f4 __attribute__((ext_vector_type(4)));

namespace {
constexpr int MM    = 68;
constexpr int IN_D  = 256;
constexpr int OUT_D = 4608;
constexpr int TT    = 16;              // tokens per block
constexpr int QT    = 4;               // tokens per quarter
constexpr int NTH   = 256;
constexpr int NJ    = 5;
constexpr int XROW  = IN_D + 4;        // 260 floats: x row stride in LDS
constexpr int TPAD  = 4 * MM + 4;      // 276 floats: t1 row stride
constexpr int RPF4  = NJ * 5 * NTH;    // 6400 f4 = 102,400 B in ws
}

// ---------------- one-time R/bias repack: Rp[(j*5+q)*256 + tid] ----------------
__global__ __launch_bounds__(NTH, 1)
void pack_R(const float* __restrict__ R, const float* __restrict__ bias,
            f4* __restrict__ Rp)
{
  const int jq  = blockIdx.x;            // 0..24 = (j,q)
  const int j   = jq / 5;
  const int q   = jq - 5 * j;
  const int tid = threadIdx.x;
  const int g   = tid / 17;
  const int m   = tid - g * 17;
  const int l4  = 4 * m;
  const int s   = g + 15 * j;
  const bool act = (tid < 255) && (s < MM) && (s < MM - 1 || m < 13);
  f4 v = {0.f, 0.f, 0.f, 0.f};
  if (act) {
    if (q < 4) v = *(const f4*)(R + (size_t)(l4 + q) * (MM * MM) + (size_t)s * MM);
    else       v = *(const f4*)(bias + s * MM + l4);
  }
  Rp[jq * NTH + tid] = v;
}

// A dot worker (r16 verbatim): NLI compile-time, p4max runtime.
template <int NLI>
__device__ __forceinline__ void dotA(const float* __restrict__ xls,
                                     const float* __restrict__ Lrow0,
                                     float* __restrict__ t1w, int p4m)
{
  float acc[NLI];
#pragma unroll
  for (int li = 0; li < NLI; ++li) acc[li] = 0.f;

#pragma unroll 1
  for (int p4 = 0; p4 < p4m; ++p4) {
    f4 xv = *(const f4*)(xls + 4 * p4);            // LDS broadcast
    f4 Lv[NLI];
#pragma unroll
    for (int li = 0; li < NLI; ++li)               // independent L2-hot loads
      Lv[li] = *(const f4*)(Lrow0 + (size_t)li * MM + 4 * p4);
#pragma unroll
    for (int li = 0; li < NLI; ++li) {
      acc[li] = fmaf(xv.x, Lv[li].x, acc[li]);
      acc[li] = fmaf(xv.y, Lv[li].y, acc[li]);
      acc[li] = fmaf(xv.z, Lv[li].z, acc[li]);
      acc[li] = fmaf(xv.w, Lv[li].w, acc[li]);
    }
  }
#pragma unroll
  for (int li = 0; li < NLI; ++li) t1w[li] = acc[li];
}

template <bool USE_RP>
__global__ __launch_bounds__(NTH, 4)
void monarch_pipe(const float* __restrict__ x, const float* __restrict__ L,
                  const float* __restrict__ R, const float* __restrict__ bias,
                  const f4* __restrict__ Rp, float* __restrict__ out)
{
  __shared__ float xs[TT * XROW];        // 16,640 B
  __shared__ float t1s[TT * TPAD];       // 17,664 B
  const int tid = threadIdx.x;
  const long tb = (long)blockIdx.x * TT;

  // ---- stage x -> LDS (coalesced, all 16 tokens) ----
#pragma unroll
  for (int k = 0; k < (TT * IN_D / 4) / NTH; ++k) {
    int i   = k * NTH + tid;
    int tok = i >> 6;
    int pos = i & 63;
    *(f4*)(&xs[tok * XROW + 4 * pos]) = *(const f4*)(x + (tb + tok) * IN_D + 4 * pos);
  }

  // ---- A-quarter thread mapping: tok(2b) | combo(4b) | liq(2b) ----
  const int atok = tid & 3;
  const int acb  = (tid >> 2) & 15;
  const int ar   = acb >> 2;
  const int alq  = acb & 3;
  const int liq  = tid >> 6;                       // wave-uniform
  const int li0  = (liq == 0) ? 0 : (4 * liq + 1); // 0,5,9,13
  const int ap4m = (ar == 3) ? 13 : 17;
  const float* axls = &xs[atok * XROW + ar * MM];
  const float* aL0  = L + (size_t)(ar * MM + alq * 17 + li0) * MM;
  float*       at1w = &t1s[atok * TPAD + ar * MM + alq * 17 + li0];

  // ---- B thread mapping ----
  const int g  = tid / 17;
  const int m  = tid - g * 17;
  const int l4 = 4 * m;

  __syncthreads();                                 // xs ready

  if (liq == 0) dotA<5>(axls, aL0, at1w, ap4m);    // A(q=0)
  else          dotA<4>(axls, aL0, at1w, ap4m);
  __syncthreads();                                 // quarter 0 t1 ready

#pragma unroll 1
  for (int q = 0; q < TT / QT; ++q) {
    // ---- B(q): tokens 4q..4q+3, coalesced Rp operand loads ----
#pragma unroll 1
    for (int j = 0; j < NJ; ++j) {
      const int s = g + 15 * j;
      const bool act = (tid < 255) && (s < MM) && (s < MM - 1 || m < 13);
      const int scol = s * MM + l4;
      f4 R0, R1, R2, R3, bv;
      if (USE_RP) {                       // 1KB lane-contiguous loads, L2-hot
        R0 = Rp[(j * 5 + 0) * NTH + tid];
        R1 = Rp[(j * 5 + 1) * NTH + tid];
        R2 = Rp[(j * 5 + 2) * NTH + tid];
        R3 = Rp[(j * 5 + 3) * NTH + tid];
        bv = Rp[(j * 5 + 4) * NTH + tid];
      } else if (act) {                   // fallback: 64-line scatters
        R0 = *(const f4*)(R + (size_t)(l4 + 0) * (MM * MM) + (size_t)s * MM);
        R1 = *(const f4*)(R + (size_t)(l4 + 1) * (MM * MM) + (size_t)s * MM);
        R2 = *(const f4*)(R + (size_t)(l4 + 2) * (MM * MM) + (size_t)s * MM);
        R3 = *(const f4*)(R + (size_t)(l4 + 3) * (MM * MM) + (size_t)s * MM);
        bv = *(const f4*)(bias + scol);
      }
#pragma unroll
      for (int ti = 0; ti < QT; ++ti) {
        const int t = q * QT + ti;
        if (act) {
          const float* t1p = t1s + t * TPAD + l4;
          f4 a0 = *(const f4*)(t1p);
          f4 a1 = *(const f4*)(t1p + MM);
          f4 a2 = *(const f4*)(t1p + 2 * MM);
          f4 a3 = *(const f4*)(t1p + 3 * MM);
          f4 o;
          o.x = fmaf(a3.x, R0.w, fmaf(a2.x, R0.z, fmaf(a1.x, R0.y, fmaf(a0.x, R0.x, bv.x))));
          o.y = fmaf(a3.y, R1.w, fmaf(a2.y, R1.z, fmaf(a1.y, R1.y, fmaf(a0.y, R1.x, bv.y))));
          o.z = fmaf(a3.z, R2.w, fmaf(a2.z, R2.z, fmaf(a1.z, R2.y, fmaf(a0.z, R2.x, bv.z))));
          o.w = fmaf(a3.w, R3.w, fmaf(a2.w, R3.z, fmaf(a1.w, R3.y, fmaf(a0.w, R3.x, bv.w))));
          *(f4*)(out + (tb + t) * OUT_D + scol) = o;
        }
      }
    }
    // ---- A(q+1): overlaps B(q)'s store drain (vmcnt drained only at barrier) ----
    if (q < TT / QT - 1) {
      const float* xq = axls + (q + 1) * QT * XROW;
      float*       tq = at1w + (q + 1) * QT * TPAD;
      if (liq == 0) dotA<5>(xq, aL0, tq, ap4m);
      else          dotA<4>(xq, aL0, tq, ap4m);
      __syncthreads();                             // quarter q+1 t1 ready
    }
  }
}

extern "C" void kernel_launch(void* const* d_in, const int* in_sizes, int n_in,
                              void* d_out, int out_size, void* d_ws, size_t ws_size,
                              hipStream_t stream) {
  const float* x    = (const float*)d_in[0];
  const float* L    = (const float*)d_in[1];
  const float* R    = (const float*)d_in[2];
  const float* bias = (const float*)d_in[3];
  float* out = (float*)d_out;

  const int ntok = in_sizes[0] / IN_D;     // 16384

  if (ws_size >= (size_t)RPF4 * sizeof(f4)) {
    f4* Rp = (f4*)d_ws;
    pack_R<<<NJ * 5, NTH, 0, stream>>>(R, bias, Rp);
    monarch_pipe<true><<<ntok / TT, NTH, 0, stream>>>(x, L, R, bias, Rp, out);
  } else {
    monarch_pipe<false><<<ntok / TT, NTH, 0, stream>>>(x, L, R, bias, nullptr, out);
  }
}